// Round 2
// baseline (81.080 us; speedup 1.0000x reference)
//
#include <hip/hip_runtime.h>

#define NW 10

typedef float v2f __attribute__((ext_vector_type(2)));

// DPP: quad_perm xor1=0xB1, xor2=0x4E; row_ror:8 (xor8 within 16) = 0x128
template<int CTRL>
__device__ __forceinline__ float fdpp(float v) {
    return __int_as_float(__builtin_amdgcn_mov_dpp(__float_as_int(v), CTRL, 0xF, 0xF, true));
}
// ds_swizzle BitMode: xor4=0x101F, xor16=0x401F
template<int PAT>
__device__ __forceinline__ float fswz(float v) {
    return __int_as_float(__builtin_amdgcn_ds_swizzle(__float_as_int(v), PAT));
}
__device__ __forceinline__ float fbperm(int addr, float v) {
    return __int_as_float(__builtin_amdgcn_ds_bpermute(addr, __float_as_int(v)));
}

// ---------------- precompute: 7 folded diag tables (cs,sn) + 80 RY (cos,sin) ----
// Fold rule: D2 . P(D1 . s)[u] = (D2[u]*D1[P(u)])*s[P(u)], P(s)=s^(s>>1)^((s&1)*0x300).
// d<4 : T1[k=d]   = rz3_k(s)*rz2_k(P(s))       (applied post-perm)
// d<7 : T2[k=d-4] = rz0_{k+1}(s)*rz5_k(P(s))   (applied post-perm with x-phase)
// Table array index j: lane=j&63, r=(j>>6)&3, W=j>>8; entry is for position
// index s = (W<<8)|(lane<<2)|r.
__global__ void precompute_kernel(const float* __restrict__ params, float2* __restrict__ tab) {
    const int j = blockIdx.x * 256 + threadIdx.x;
    if (j < 7 * 1024) {
        const int d = j >> 10, jj = j & 1023;
        const int W = jj >> 8, lane = jj & 63, r = (jj >> 6) & 3;
        const int s = (W << 8) | (lane << 2) | r;
        const int q = s ^ (s >> 1) ^ ((s & 1) * 0x300);
        const float* thA;
        const float* thB;
        if (d < 4) {
            thA = params + (d * 6 + 3) * NW;          // rz3 of block d
            thB = params + (d * 6 + 2) * NW;          // rz2 of block d
        } else {
            const int k = d - 4;
            thA = params + ((k + 1) * 6 + 0) * NW;    // rz0 of block k+1
            thB = params + (k * 6 + 5) * NW;          // rz5 of block k
        }
        float ang = 0.f;
#pragma unroll
        for (int w = 0; w < NW; ++w) {
            ang += thA[w] * (((s >> (9 - w)) & 1) ? 0.5f : -0.5f);
            ang += thB[w] * (((q >> (9 - w)) & 1) ? 0.5f : -0.5f);
        }
        float sn, cs;
        __sincosf(ang, &sn, &cs);
        tab[j] = make_float2(cs, sn);
    } else if (j < 7 * 1024 + 80) {
        const int i = j - 7 * 1024;
        const int ry = i / NW, w = i % NW;
        const int k = ry >> 1, ii = ry & 1;
        const float* th = params + (k * 6 + (ii ? 4 : 1)) * NW;
        float sn, cs;
        __sincosf(0.5f * th[w], &sn, &cs);
        tab[7 * 1024 + i] = make_float2(cs, sn);
    }
}

// ---------------- main kernel: 1 wave = 1 sample, 16 amps/lane, 0 barriers ----
// Position bits of element index s (s = x9..x0):
//   x0=u0 x1=u1 (reg bits, m=1,2) | x2..x7 = lane bits l0..l5 | x8=u2 x9=u3 (reg, m=4,8)
// Wire w lives at position 9-w:
//   w9:u0  w8:u1  w7:l0(xor1 DPP)  w6:l1(xor2 DPP)  w5:l2(xor4 swz)
//   w4:l3(xor8 DPP)  w3:l4(xor16 swz)  w2:l5(xor32 shfl)  w1:u2  w0:u3
// Perm y=P(x): y0=x0^x1, y1=x1^x2, y2=x2^x3, y3=x3^x4, y4=x4^x5, y5=x5^x6,
//   y6=x6^x7, y7=x7^x8, y8=x8^x9^x0, y9=x9^x0  (matches precompute's q fold).
// Gather for dest (u,lane):
//   src lane = (l0^l1)|((l1^l2)<<1)|((l2^l3)<<2)|((l3^l4)<<3)|((l4^l5)<<4)|((l5^u2)<<5)
//   src reg  = (u0^u1) | ((u1^d0)<<1) | ((u0^u2^u3)<<2) | ((u0^u3)<<3)
// where d0 is the CONSUMER's lane bit0. ds_bpermute is a pull, so each PROVIDER
// lane s must supply the register its unique consumer d=L^{-1}(s) wants:
//   d0 = s0^s1^s2^s3^s4^s5 ^ u2  (parity of provider's lane bits ^ u2).

#define DPP_STAGE(CTRL, CW, BIT) do {                                          \
    const float2 cw_ = (CW);                                                   \
    const float ss_ = (lane & (BIT)) ? cw_.y : -cw_.y;                         \
    _Pragma("unroll")                                                          \
    for (int u_ = 0; u_ < 16; ++u_) {                                          \
        v2f p_;                                                                \
        p_.x = fdpp<CTRL>(st[u_].x);                                           \
        p_.y = fdpp<CTRL>(st[u_].y);                                           \
        st[u_] = cw_.x * st[u_] + ss_ * p_;                                    \
    }                                                                          \
} while (0)

#define SWZ_STAGE(PAT, CW, BIT) do {                                           \
    const float2 cw_ = (CW);                                                   \
    const float ss_ = (lane & (BIT)) ? cw_.y : -cw_.y;                         \
    v2f p_[16];                                                                \
    _Pragma("unroll")                                                          \
    for (int u_ = 0; u_ < 16; ++u_) {                                          \
        p_[u_].x = fswz<PAT>(st[u_].x);                                        \
        p_[u_].y = fswz<PAT>(st[u_].y);                                        \
    }                                                                          \
    _Pragma("unroll")                                                          \
    for (int u_ = 0; u_ < 16; ++u_) st[u_] = cw_.x * st[u_] + ss_ * p_[u_];    \
} while (0)

#define X32_STAGE(CW) do {                                                     \
    const float2 cw_ = (CW);                                                   \
    const float ss_ = (lane & 32) ? cw_.y : -cw_.y;                            \
    v2f p_[16];                                                                \
    _Pragma("unroll")                                                          \
    for (int u_ = 0; u_ < 16; ++u_) {                                          \
        p_[u_].x = __shfl_xor(st[u_].x, 32, 64);                               \
        p_[u_].y = __shfl_xor(st[u_].y, 32, 64);                               \
    }                                                                          \
    _Pragma("unroll")                                                          \
    for (int u_ = 0; u_ < 16; ++u_) st[u_] = cw_.x * st[u_] + ss_ * p_[u_];    \
} while (0)

__global__ __launch_bounds__(256, 2) void qsim_kernel(const float* __restrict__ x,
                                                      const float2* __restrict__ tab,
                                                      float* __restrict__ out) {
    const int t    = threadIdx.x;
    const int W    = t >> 6;
    const int lane = t & 63;
    const int b    = blockIdx.x * 4 + W;           // one sample per wave
    const float2* ry_tab = tab + 7 * 1024;

    const int l0 = lane & 1, l1 = (lane >> 1) & 1, l2 = (lane >> 2) & 1,
              l3 = (lane >> 3) & 1, l4 = (lane >> 4) & 1, l5 = (lane >> 5) & 1;

    // perm bpermute addresses (byte addr = src_lane*4); pa1 = u2-flipped (bit5)
    const int lp = (l0 ^ l1) | ((l1 ^ l2) << 1) | ((l2 ^ l3) << 2)
                 | ((l3 ^ l4) << 3) | ((l4 ^ l5) << 4) | (l5 << 5);
    const int pa0 = lp << 2;
    const int pa1 = pa0 ^ 128;
    const int par = l0 ^ l1 ^ l2 ^ l3 ^ l4 ^ l5;   // consumer's d0 = par ^ u2

    v2f st[16];
    float2 xp[16];
    float2 tq[16];

    // x-phase e^{iA_x(s)} per register: ang(s) = -A/2 + sum over set bits of xv[wire]
    {
        const float* xb = x + b * NW;
        float xv[NW];
#pragma unroll
        for (int w = 0; w < NW; ++w) xv[w] = xb[w];
        float A = 0.f;
#pragma unroll
        for (int w = 0; w < NW; ++w) A += xv[w];
        float hb = -0.5f * A;
        if (l0) hb += xv[7];
        if (l1) hb += xv[6];
        if (l2) hb += xv[5];
        if (l3) hb += xv[4];
        if (l4) hb += xv[3];
        if (l5) hb += xv[2];
#pragma unroll
        for (int u = 0; u < 16; ++u) {
            float ang = hb;
            if (u & 1) ang += xv[9];
            if (u & 2) ang += xv[8];
            if (u & 4) ang += xv[1];
            if (u & 8) ang += xv[0];
            float sn, cs;
            __sincosf(ang, &sn, &cs);
            xp[u] = make_float2(cs, sn);
        }
    }

    // prefetch folded-diag entries; array index = lane | (u&3)<<6 | (u>>2)<<8
    auto pre = [&](int d) {
        const float2* tb = tab + (d << 10) + lane;
#pragma unroll
        for (int u = 0; u < 16; ++u)
            tq[u] = tb[((u & 3) << 6) | ((u >> 2) << 8)];
    };

    // analytic init: amp(s) = prod_w (bit_{9-w}(s) ? sin_w : cos_w), ridx 0
    auto initC = [&]() {
        const float2 r9 = ry_tab[9], r8 = ry_tab[8], r7 = ry_tab[7], r6 = ry_tab[6],
                     r5 = ry_tab[5], r4 = ry_tab[4], r3 = ry_tab[3], r2 = ry_tab[2],
                     r1 = ry_tab[1], r0 = ry_tab[0];
        float P6 = (l0 ? r7.y : r7.x) * (l1 ? r6.y : r6.x) * (l2 ? r5.y : r5.x)
                 * (l3 ? r4.y : r4.x) * (l4 ? r3.y : r3.x) * (l5 ? r2.y : r2.x);
#pragma unroll
        for (int u = 0; u < 16; ++u) {
            float v = P6 * ((u & 1) ? r9.y : r9.x) * ((u & 2) ? r8.y : r8.x)
                         * ((u & 4) ? r1.y : r1.x) * ((u & 8) ? r0.y : r0.x);
            st[u] = (v2f){v, 0.f};
        }
    };

    // register-local butterfly on reg-bit m
    auto bflyL = [&](float2 cw, int m) {
#pragma unroll
        for (int u = 0; u < 16; ++u)
            if (!(u & m)) {
                const int v = u | m;
                const v2f a = st[u];
                st[u] = cw.x * a - cw.y * st[v];
                st[v] = cw.y * a + cw.x * st[v];
            }
    };

    // full 10-wire RY, all intra-wave, no barriers
    auto ry = [&](int ridx) {
        const float2* rt = ry_tab + ridx * NW;
        bflyL(rt[9], 1);                 // w9: u0
        bflyL(rt[8], 2);                 // w8: u1
        bflyL(rt[1], 4);                 // w1: u2
        bflyL(rt[0], 8);                 // w0: u3
        DPP_STAGE(0xB1, rt[7], 1);       // w7: l0 xor1
        DPP_STAGE(0x4E, rt[6], 2);       // w6: l1 xor2
        SWZ_STAGE(0x101F, rt[5], 4);     // w5: l2 xor4
        DPP_STAGE(0x128, rt[4], 8);      // w4: l3 xor8
        SWZ_STAGE(0x401F, rt[3], 16);    // w3: l4 xor16
        X32_STAGE(rt[2]);                // w2: l5 xor32
    };

    // perm gather fused with diag apply (mode1 also multiplies x-phase)
    auto permApply = [&](int mode) {
        v2f ns[16];
#pragma unroll
        for (int u = 0; u < 16; ++u) {
            const int u0 = u & 1, u1 = (u >> 1) & 1, u2 = (u >> 2) & 1, u3 = (u >> 3) & 1;
            const int a = (u0 ^ u1) | (u1 << 1) | ((u0 ^ u2 ^ u3) << 2) | ((u0 ^ u3) << 3);
            const v2f v = (par ^ u2) ? st[a ^ 2] : st[a];   // provider supplies for its consumer
            const int ad = u2 ? pa1 : pa0;
            ns[u].x = fbperm(ad, v.x);
            ns[u].y = fbperm(ad, v.y);
        }
#pragma unroll
        for (int u = 0; u < 16; ++u) {
            float cx = tq[u].x, cy = tq[u].y;
            if (mode) {
                const float tx = cx, ty = cy;
                cx = tx * xp[u].x - ty * xp[u].y;
                cy = tx * xp[u].y + ty * xp[u].x;
            }
            st[u] = (v2f){cx * ns[u].x - cy * ns[u].y,
                          cy * ns[u].x + cx * ns[u].y};
        }
    };

#pragma unroll 1
    for (int k = 0; k < 4; ++k) {
        pre(k);                          // T1[k]
        if (k == 0) initC();             // |0> -> ry(0) product state
        else        ry(2 * k);
        permApply(0);                    // perm + rz2.P * rz3
        if (k < 3) pre(4 + k);           // T2[k]
        ry(2 * k + 1);
        if (k < 3) permApply(1);         // perm + rz5.P * rz0(k+1) * enc(x)
        // k==3: rz5 pure phase (dropped); final perm folded into epilogue signs.
    }

    // ---- epilogue: out[w] = sum_e (-1)^{x_{9-w}(P^{-1}(e))} |st(e)|^2
    // P^{-1}: x8=y8^y9; x_j = y_j^...^y7^y8^y9 (j<=7); x9 = y0^...^y8.
    // Reg Walsh combos over (u0,u1,u2,u3) = (y0,y1,y8,y9):
    float pr[16];
#pragma unroll
    for (int u = 0; u < 16; ++u) pr[u] = st[u].x * st[u].x + st[u].y * st[u].y;

    float q0[4], q1[4], q2[4];
#pragma unroll
    for (int g = 0; g < 4; ++g) {
        const float a = pr[4 * g] + pr[4 * g + 1], bb = pr[4 * g + 2] + pr[4 * g + 3];
        const float c = pr[4 * g] - pr[4 * g + 1], d = pr[4 * g + 2] - pr[4 * g + 3];
        q0[g] = a + bb;   // sum over u0,u1
        q1[g] = a - bb;   // (-1)^{u1}
        q2[g] = c - d;    // (-1)^{u0^u1}
    }
    const float R23   = q0[0] - q0[1] - q0[2] + q0[3];   // (-1)^{u2^u3}
    const float R123  = q1[0] - q1[1] - q1[2] + q1[3];   // (-1)^{u1^u2^u3}
    const float R0123 = q2[0] - q2[1] - q2[2] + q2[3];   // (-1)^{u0^u1^u2^u3}
    const float R012  = q2[0] - q2[1] + q2[2] - q2[3];   // (-1)^{u0^u1^u2}

    // lane suffix parities over l5..l0 (= y7..y2)
    const int P5 = l5, P4 = l4 ^ P5, P3 = l3 ^ P4, P2 = l2 ^ P3, P1 = l1 ^ P2, P0 = l0 ^ P1;

    float acc[NW];
    acc[0] = P0 ? -R012 : R012;    // x9 = y0..y8
    acc[1] = R23;                  // x8 = y8^y9
    acc[2] = P5 ? -R23 : R23;      // x7 = y7^y8^y9
    acc[3] = P4 ? -R23 : R23;      // x6
    acc[4] = P3 ? -R23 : R23;      // x5
    acc[5] = P2 ? -R23 : R23;      // x4
    acc[6] = P1 ? -R23 : R23;      // x3
    acc[7] = P0 ? -R23 : R23;      // x2
    acc[8] = P0 ? -R123 : R123;    // x1 = y1..y9
    acc[9] = P0 ? -R0123 : R0123;  // x0 = y0..y9

#pragma unroll
    for (int w = 0; w < NW; ++w) {
        float a = acc[w];
        a += fdpp<0xB1>(a);
        a += fdpp<0x4E>(a);
        a += fswz<0x101F>(a);
        a += fdpp<0x128>(a);
        a += fswz<0x401F>(a);
        a += __shfl_xor(a, 32, 64);
        acc[w] = a;
    }
    if (lane == 0) {
        float2* o = (float2*)(out + b * NW);
        o[0] = make_float2(acc[0], acc[1]);
        o[1] = make_float2(acc[2], acc[3]);
        o[2] = make_float2(acc[4], acc[5]);
        o[3] = make_float2(acc[6], acc[7]);
        o[4] = make_float2(acc[8], acc[9]);
    }
}

extern "C" void kernel_launch(void* const* d_in, const int* in_sizes, int n_in,
                              void* d_out, int out_size, void* d_ws, size_t ws_size,
                              hipStream_t stream) {
    const float* x      = (const float*)d_in[0];   // (2048, 10)
    const float* params = (const float*)d_in[1];   // (4, 6, 10)
    float* out          = (float*)d_out;           // (1, 2048, 10)
    float2* tab         = (float2*)d_ws;           // 7*1024+80 float2 = 57 KB
    (void)in_sizes; (void)n_in; (void)out_size; (void)ws_size;
    precompute_kernel<<<29, 256, 0, stream>>>(params, tab);
    qsim_kernel<<<512, 256, 0, stream>>>(x, tab, out);
}